// Round 8
// baseline (231.637 us; speedup 1.0000x reference)
//
#include <hip/hip_runtime.h>
#include <math.h>

#define DD   128      // hidden dim
#define LL   32       // sequence length
#define MS   32       // sequences per block
#define NT   512      // 8 waves: 4 consumer (32 dims each) + 4 producer
#define NSEQ 8192     // B*S
#define XP   136      // h LDS row pitch in ushorts (272 B, 16B-aligned)
#define OLP  36       // outl pitch in floats

// gx handoff: raw C-fragments [2 slots][48 tiles][64 lanes] x f32x4,
// tile = ((g*4 + w)*2 + sl)*2 + st  (g 0..2 gate, w 0..3 dim-quarter,
// sl 0..1 slice-within-quarter, st 0..1 seq-tile). Lane-linear 16B/lane ->
// contiguous 1KB wave access, bank-conflict-free.
#define NFRAG      48
#define FRAGF      (NFRAG * 64 * 4)                   // 12288 f32 per slot
#define SMEM_XHH   (2 * FRAGF * 4)                    // 98304
#define SMEM_PP    (SMEM_XHH + 2 * MS * XP * 2)       // +17408 = 115712
#define SMEM_OUTL  (SMEM_PP + 2 * 2 * 4 * 16 * 4)     // +1024  = 116736
#define SMEM_TOTAL (SMEM_OUTL + MS * OLP * 4)         // +4608  = 121344

typedef short bf16x8 __attribute__((ext_vector_type(8)));   // 8 bf16 = 4 VGPRs
typedef float f32x4  __attribute__((ext_vector_type(4)));

// Transposed orientation (r2-proven): A = weights (row = gate-dim),
// B = x/h (col = seq); C: col(lane&15)=seq, row((lane>>4)*4+i)=dim.
#define MFMA __builtin_amdgcn_mfma_f32_16x16x32_bf16

// lgkm-only barrier: orders LDS exchange without draining vmcnt, so the
// producers' wave-private global x prefetch stays in flight across it
// (HK 8-phase pattern, m201). Trailing empty asm = anti-hoist fence.
#define BARRIER() do {                                             \
    asm volatile("s_waitcnt lgkmcnt(0)" ::: "memory");             \
    __builtin_amdgcn_s_barrier();                                  \
    asm volatile("" ::: "memory");                                 \
} while (0)

__device__ __forceinline__ unsigned short f2bf(float f) {
    unsigned u = __float_as_uint(f);
    u += 0x7fffu + ((u >> 16) & 1u);          // round-to-nearest-even
    return (unsigned short)(u >> 16);
}

#if __has_builtin(__builtin_amdgcn_cvt_pk_bf16_f32)
typedef __bf16 bf16x2_t __attribute__((ext_vector_type(2)));
__device__ __forceinline__ unsigned pack2(float a, float b) {
    union { bf16x2_t v; unsigned u; } c;
    c.v = __builtin_amdgcn_cvt_pk_bf16_f32(a, b);
    return c.u;
}
#else
__device__ __forceinline__ unsigned pack2(float a, float b) {
    return (unsigned)f2bf(a) | ((unsigned)f2bf(b) << 16);
}
#endif

__device__ __forceinline__ void pack8(float4 a, float4 b, unsigned short* dst) {
    union { unsigned u[4]; bf16x8 v; } pk;
    pk.u[0] = pack2(a.x, a.y); pk.u[1] = pack2(a.z, a.w);
    pk.u[2] = pack2(b.x, b.y); pk.u[3] = pack2(b.z, b.w);
    *(bf16x8*)dst = pk.v;
}

__device__ __forceinline__ bf16x8 pack8r(float4 a, float4 b) {
    union { unsigned u[4]; bf16x8 v; } pk;
    pk.u[0] = pack2(a.x, a.y); pk.u[1] = pack2(a.z, a.w);
    pk.u[2] = pack2(b.x, b.y); pk.u[3] = pack2(b.z, b.w);
    return pk.v;
}

__device__ __forceinline__ float fast_rcp(float x) {
    return __builtin_amdgcn_rcpf(x);   // v_rcp_f32, ~1 ulp — fine at bf16 output
}

// ---------------------------------------------------------------------------
// Prep: swizzle W_ih / W_hh into per-gate MFMA fragments, bf16. (unchanged)
// Frag index F = ((side*3 + g)*8 + sl)*4 + kk   (side 0=W_ih, 1=W_hh;
// g 0=r,1=z,2=n; sl = 16-dim slice 0..7; kk = K-subtile 0..3).
// Element j of lane (n=lane&15, q=lane>>4):
//   W_side[(g*128 + sl*16 + n) * 128 + (kk*32 + q*8 + j)]
// ---------------------------------------------------------------------------
__global__ void prep_weights(const float* __restrict__ Wih,
                             const float* __restrict__ Whh,
                             unsigned short* __restrict__ Wfrag) {
    int idx  = blockIdx.x * blockDim.x + threadIdx.x;   // 0 .. 98303
    int j    = idx & 7;
    int lane = (idx >> 3) & 63;
    int kk   = (idx >> 9) & 3;
    int sl   = (idx >> 11) & 7;
    int sg   = idx >> 14;            // 0..5 = side*3 + g
    int n = lane & 15, q = lane >> 4;
    int k  = kk * 32 + q * 8 + j;
    int g  = (sg >= 3) ? sg - 3 : sg;
    int gd = g * 128 + sl * 16 + n;
    const float* src = (sg >= 3) ? Whh : Wih;
    Wfrag[idx] = f2bf(src[gd * 128 + k]);
}

// ---------------------------------------------------------------------------
// 8-wave wave-specialized GRU, LDS-phase-minimized:
//   waves 0..3 (consumer): 32 gate-dims each; h-GEMM + gate math + h-write
//       + f32 out-partial (dot + shfl-reduce -> Pp).
//   waves 4..7 (producer): x B-frags built DIRECTLY from global f32 loads in
//       registers (no xhx LDS); x-GEMM one step ahead into the gx frag ring;
//       wave 7 assembles out columns from Pp.
// Consolidation halves the h B-frag LDS reads (4 readers, not 8); direct-x
// deletes the x LDS round-trip; lgkm-only barrier keeps the x prefetch in
// flight across steps. One weight copy across 8 waves (~250 VGPR, 2/SIMD).
// TRIPWIRE: FETCH >> 140 MB or WRITE >> 1 MB => spill => run void.
// ---------------------------------------------------------------------------
__global__ __launch_bounds__(NT, 2) void gru_mfma(
    const float* __restrict__ x,      // [8192][32][128]
    const float* __restrict__ h0,     // [8192][128]
    const unsigned short* __restrict__ Wfrag,
    const float* __restrict__ b_ih,   // [384]
    const float* __restrict__ b_hh,   // [384]
    const float* __restrict__ w_out,  // [128]
    const float* __restrict__ b_out,  // [1]
    float* __restrict__ out)          // [8192][32]
{
    extern __shared__ char smem[];
    float*          gxf  = (float*)(smem);                       // [2][48][64][4]
    unsigned short* xhh  = (unsigned short*)(smem + SMEM_XHH);   // [2][MS][XP]
    float*          Pp   = (float*)(smem + SMEM_PP);             // [2][2][4][16]
    float*          outl = (float*)(smem + SMEM_OUTL);           // [MS][OLP]

    const int tid  = threadIdx.x;
    const int n0   = blockIdx.x * MS;
    const int wv   = tid >> 6;       // 0..7
    const int lane = tid & 63;
    const int ln   = lane & 15;      // C col = seq within tile
    const int q    = lane >> 4;      // C rows q*4..q*4+3 = gate-dims
    const bf16x8* W = (const bf16x8*)Wfrag;

    if (wv < 4) {
        // ================= CONSUMER (32 dims: slices 2wv, 2wv+1) ============
        const int cw = wv;

        bf16x8 whr[2][4], whz[2][4], whn[2][4];    // W_hh A-operands
        #pragma unroll
        for (int sl = 0; sl < 2; ++sl)
            #pragma unroll
            for (int kk = 0; kk < 4; ++kk) {
                whr[sl][kk] = W[((24 + cw*2 + sl)*4 + kk)*64 + lane];
                whz[sl][kk] = W[((32 + cw*2 + sl)*4 + kk)*64 + lane];
                whn[sl][kk] = W[((40 + cw*2 + sl)*4 + kk)*64 + lane];
            }

        // biases + w_out slices in registers
        f32x4 br4[2], bz4[2], bnx4[2], bhn4[2], wo4[2];
        #pragma unroll
        for (int sl = 0; sl < 2; ++sl) {
            const int d4 = cw*32 + sl*16 + q*4;
            br4[sl]  = *(const f32x4*)&b_ih[d4] + *(const f32x4*)&b_hh[d4];
            bz4[sl]  = *(const f32x4*)&b_ih[DD + d4] + *(const f32x4*)&b_hh[DD + d4];
            bnx4[sl] = *(const f32x4*)&b_ih[2*DD + d4];
            bhn4[sl] = *(const f32x4*)&b_hh[2*DD + d4];
            wo4[sl]  = *(const f32x4*)&w_out[d4];
        }

        // stage h0 (bf16) into xhh slot 0: 256 consumer threads x 16 dims
        {
            const int gn = tid >> 3, gd16 = (tid & 7) * 16;
            const float* hb = h0 + (size_t)(n0 + gn) * DD + gd16;
            pack8(*(const float4*)hb, *(const float4*)(hb + 4),
                  &xhh[gn * XP + gd16]);
            pack8(*(const float4*)(hb + 8), *(const float4*)(hb + 12),
                  &xhh[gn * XP + gd16 + 8]);
        }
        // fp32 hidden state: [st][sl][i], lane = seq ln within tile st
        float hprev[2][2][4];
        #pragma unroll
        for (int st = 0; st < 2; ++st)
            #pragma unroll
            for (int sl = 0; sl < 2; ++sl) {
                float4 hp = *(const float4*)
                    &h0[(size_t)(n0 + st*16 + ln) * DD + cw*32 + sl*16 + q*4];
                hprev[st][sl][0] = hp.x; hprev[st][sl][1] = hp.y;
                hprev[st][sl][2] = hp.z; hprev[st][sl][3] = hp.w;
            }

        BARRIER();   // #1: h0 staged + gx[0] written

        #pragma unroll 2
        for (int t = 0; t < LL; ++t) {
            const int cur = t & 1;
            const float* gf = gxf + cur * FRAGF;
            f32x4 cr[2][2], cz[2][2], ch[2][2];
            #pragma unroll
            for (int sl = 0; sl < 2; ++sl)
                #pragma unroll
                for (int st = 0; st < 2; ++st) {
                    cr[sl][st] = *(const f32x4*)
                        &gf[((((0*4 + cw)*2 + sl)*2 + st)*64 + lane)*4];
                    cz[sl][st] = *(const f32x4*)
                        &gf[((((1*4 + cw)*2 + sl)*2 + st)*64 + lane)*4];
                    ch[sl][st] = bhn4[sl];       // b_hn folded into acc init
                }
            const unsigned short* hr0 = xhh + cur*MS*XP + ln*XP;
            const unsigned short* hr1 = hr0 + 16*XP;
            #pragma unroll
            for (int kk = 0; kk < 4; ++kk) {
                bf16x8 b0 = *(const bf16x8*)(hr0 + kk*32 + q*8);
                bf16x8 b1 = *(const bf16x8*)(hr1 + kk*32 + q*8);
                #pragma unroll
                for (int sl = 0; sl < 2; ++sl) {
                    cr[sl][0] = MFMA(whr[sl][kk], b0, cr[sl][0], 0,0,0);
                    cr[sl][1] = MFMA(whr[sl][kk], b1, cr[sl][1], 0,0,0);
                    cz[sl][0] = MFMA(whz[sl][kk], b0, cz[sl][0], 0,0,0);
                    cz[sl][1] = MFMA(whz[sl][kk], b1, cz[sl][1], 0,0,0);
                    ch[sl][0] = MFMA(whn[sl][kk], b0, ch[sl][0], 0,0,0);
                    ch[sl][1] = MFMA(whn[sl][kk], b1, ch[sl][1], 0,0,0);
                }
            }
            // n-gate x-side preacts read late (short live range)
            f32x4 gnx[2][2];
            #pragma unroll
            for (int sl = 0; sl < 2; ++sl)
                #pragma unroll
                for (int st = 0; st < 2; ++st)
                    gnx[sl][st] = *(const f32x4*)
                        &gf[((((2*4 + cw)*2 + sl)*2 + st)*64 + lane)*4];

            unsigned short* hw = xhh + (cur ^ 1)*MS*XP;
            float po0 = 0.f, po1 = 0.f;
            #pragma unroll
            for (int st = 0; st < 2; ++st)
                #pragma unroll
                for (int sl = 0; sl < 2; ++sl) {
                    float hh_[4];
                    #pragma unroll
                    for (int i = 0; i < 4; ++i) {
                        // shared-reciprocal double sigmoid (r4/r7-proven)
                        const float e1 = fminf(__expf(-(cr[sl][st][i] + br4[sl][i])), 1e18f);
                        const float e2 = fminf(__expf(-(cz[sl][st][i] + bz4[sl][i])), 1e18f);
                        const float p1 = 1.f + e1, p2 = 1.f + e2;
                        const float R  = fast_rcp(p1 * p2);
                        const float rr = R * p2;
                        const float zz = R * p1;
                        const float gb = gnx[sl][st][i] + bnx4[sl][i];
                        const float aa = __builtin_fmaf(rr, ch[sl][st][i], gb);
                        const float ee = __expf(-2.f * aa);   // tanh, NaN-free
                        const float th = 2.f * fast_rcp(1.f + ee) - 1.f;
                        const float hh = __builtin_fmaf(zz, hprev[st][sl][i] - th, th);
                        hprev[st][sl][i] = hh;
                        hh_[i] = hh;
                        if (st == 0) po0 = __builtin_fmaf(hh, wo4[sl][i], po0);
                        else         po1 = __builtin_fmaf(hh, wo4[sl][i], po1);
                    }
                    union { unsigned u[2]; unsigned long long ull; } hv;
                    hv.u[0] = pack2(hh_[0], hh_[1]);
                    hv.u[1] = pack2(hh_[2], hh_[3]);
                    *(unsigned long long*)
                        &hw[(st*16 + ln)*XP + cw*32 + sl*16 + q*4] = hv.ull;
                }
            // out partial: reduce over q-quads, store per (st, cw, seq)
            {
                float p0 = po0 + __shfl_xor(po0, 16); p0 += __shfl_xor(p0, 32);
                float p1_ = po1 + __shfl_xor(po1, 16); p1_ += __shfl_xor(p1_, 32);
                if (lane < 16) {
                    Pp[((cur*2 + 0)*4 + cw)*16 + ln] = p0;
                    Pp[((cur*2 + 1)*4 + cw)*16 + ln] = p1_;
                }
            }
            BARRIER();   // per-step
        }
    } else {
        // ================= PRODUCER (32 dims: slices 2pw, 2pw+1) ============
        const int pw = wv - 4;
        const float bo = b_out[0];

        bf16x8 wxr[2][4], wxz[2][4], wxn[2][4];    // W_ih A-operands
        #pragma unroll
        for (int sl = 0; sl < 2; ++sl)
            #pragma unroll
            for (int kk = 0; kk < 4; ++kk) {
                wxr[sl][kk] = W[((0  + pw*2 + sl)*4 + kk)*64 + lane];
                wxz[sl][kk] = W[((8  + pw*2 + sl)*4 + kk)*64 + lane];
                wxn[sl][kk] = W[((16 + pw*2 + sl)*4 + kk)*64 + lane];
            }

        // per-lane x row bases: lane (q,ln) loads x[seq][t][kk*32+q*8 .. +7]
        const float* xb0 = x + (size_t)(n0 + ln)      * (LL * DD);
        const float* xb1 = x + (size_t)(n0 + 16 + ln) * (LL * DD);
        float4 xf[16];   // [ (st*4+kk)*2 + half ] — all indices compile-time

#define LOADX(TT) do {                                                         \
        _Pragma("unroll")                                                      \
        for (int s_ = 0; s_ < 2; ++s_) {                                       \
            _Pragma("unroll")                                                  \
            for (int k_ = 0; k_ < 4; ++k_) {                                   \
                const float* p_ = (s_ ? xb1 : xb0)                             \
                                  + (size_t)(TT) * DD + k_*32 + q*8;           \
                xf[(s_*4 + k_)*2    ] = *(const float4*)p_;                    \
                xf[(s_*4 + k_)*2 + 1] = *(const float4*)(p_ + 4);              \
            }                                                                  \
        } } while (0)

#define GX_COMPUTE(SLOT) do {                                                  \
        f32x4 ar[2][2], az[2][2], an[2][2];                                    \
        _Pragma("unroll")                                                      \
        for (int sl = 0; sl < 2; ++sl)                                         \
            _Pragma("unroll")                                                  \
            for (int st = 0; st < 2; ++st) {                                   \
                ar[sl][st] = (f32x4){0.f,0.f,0.f,0.f};                         \
                az[sl][st] = (f32x4){0.f,0.f,0.f,0.f};                         \
                an[sl][st] = (f32x4){0.f,0.f,0.f,0.f};                         \
            }                                                                  \
        _Pragma("unroll")                                                      \
        for (int kk = 0; kk < 4; ++kk)                                         \
            _Pragma("unroll")                                                  \
            for (int st = 0; st < 2; ++st) {                                   \
                bf16x8 bx = bxf[st][kk];                                       \
                _Pragma("unroll")                                              \
                for (int sl = 0; sl < 2; ++sl) {                               \
                    ar[sl][st] = MFMA(wxr[sl][kk], bx, ar[sl][st], 0,0,0);     \
                    az[sl][st] = MFMA(wxz[sl][kk], bx, az[sl][st], 0,0,0);     \
                    an[sl][st] = MFMA(wxn[sl][kk], bx, an[sl][st], 0,0,0);     \
                }                                                              \
            }                                                                  \
        float* gw = gxf + (SLOT) * FRAGF;                                      \
        _Pragma("unroll")                                                      \
        for (int sl = 0; sl < 2; ++sl)                                         \
            _Pragma("unroll")                                                  \
            for (int st = 0; st < 2; ++st) {                                   \
                *(f32x4*)&gw[((((0*4+pw)*2+sl)*2+st)*64 + lane)*4] = ar[sl][st]; \
                *(f32x4*)&gw[((((1*4+pw)*2+sl)*2+st)*64 + lane)*4] = az[sl][st]; \
                *(f32x4*)&gw[((((2*4+pw)*2+sl)*2+st)*64 + lane)*4] = an[sl][st]; \
            } } while (0)

        // prologue: gx[0] from x_0; then issue x_1 loads (stay in flight)
        LOADX(0);
        {
            bf16x8 bxf[2][4];
            #pragma unroll
            for (int st = 0; st < 2; ++st)
                #pragma unroll
                for (int kk = 0; kk < 4; ++kk)
                    bxf[st][kk] = pack8r(xf[(st*4+kk)*2], xf[(st*4+kk)*2+1]);
            GX_COMPUTE(0);
        }
        LOADX(1);

        BARRIER();   // #1

        #pragma unroll 2
        for (int t = 0; t < LL; ++t) {
            if (t + 1 < LL) {
                // cvt x_{t+1} (loaded last iter) -> frags; issue x_{t+2};
                // x-GEMM into gx[(t+1)&1]
                bf16x8 bxf[2][4];
                #pragma unroll
                for (int st = 0; st < 2; ++st)
                    #pragma unroll
                    for (int kk = 0; kk < 4; ++kk)
                        bxf[st][kk] = pack8r(xf[(st*4+kk)*2], xf[(st*4+kk)*2+1]);
                if (t + 2 < LL) LOADX(t + 2);
                GX_COMPUTE((t + 1) & 1);
            }
            // wave 7: assemble out[t-1] from last step's partials
            if (pw == 3 && t >= 1 && lane < 32) {
                const int ps = (t & 1) ^ 1;
                float o = bo;
                #pragma unroll
                for (int c = 0; c < 4; ++c)
                    o += Pp[((ps*2 + (lane >> 4))*4 + c)*16 + (lane & 15)];
                outl[lane*OLP + (t - 1)] = o;
            }
            BARRIER();   // per-step
        }
#undef LOADX
#undef GX_COMPUTE
    }

    // epilogue: out[31] from Pp slot (31&1)=1, then coalesced flush
    if (wv == 7 && lane < 32) {
        float o = b_out[0];
        #pragma unroll
        for (int c = 0; c < 4; ++c)
            o += Pp[((1*2 + (lane >> 4))*4 + c)*16 + (lane & 15)];
        outl[lane*OLP + (LL - 1)] = o;
    }
    __syncthreads();
    if (tid < 256) {
        const int row = tid >> 3;
        const int t4  = (tid & 7) * 4;
        float4 v = *(const float4*)&outl[row*OLP + t4];
        *(float4*)(out + (size_t)(n0 + row) * LL + t4) = v;
    }
}

extern "C" void kernel_launch(void* const* d_in, const int* in_sizes, int n_in,
                              void* d_out, int out_size, void* d_ws, size_t ws_size,
                              hipStream_t stream) {
    const float* item  = (const float*)d_in[0];
    const float* user  = (const float*)d_in[1];
    const float* W_ih  = (const float*)d_in[2];
    const float* W_hh  = (const float*)d_in[3];
    const float* b_ih  = (const float*)d_in[4];
    const float* b_hh  = (const float*)d_in[5];
    const float* W_out = (const float*)d_in[6];
    const float* b_out = (const float*)d_in[7];
    float* out = (float*)d_out;

    unsigned short* Wfrag = (unsigned short*)d_ws;   // 192 frags * 512 = 98304 bf16

    static bool smem_cfg = false;
    if (!smem_cfg) {
        hipFuncSetAttribute((const void*)gru_mfma,
                            hipFuncAttributeMaxDynamicSharedMemorySize,
                            SMEM_TOTAL);
        smem_cfg = true;
    }

    prep_weights<<<384, 256, 0, stream>>>(W_ih, W_hh, Wfrag);
    gru_mfma<<<NSEQ / MS, NT, SMEM_TOTAL, stream>>>(item, user, Wfrag,
                                                    b_ih, b_hh, W_out, b_out, out);
}

// Round 9
// 220.801 us; speedup vs baseline: 1.0491x; 1.0491x over previous
//
#include <hip/hip_runtime.h>
#include <math.h>

#define DD   128      // hidden dim
#define LL   32       // sequence length
#define MS   32       // sequences per block
#define NT   1024     // 16 waves: 8 consumer + 8 producer
#define NSEQ 8192     // B*S
#define XP   136      // x/h LDS row pitch in ushorts (272 B, 16B-aligned)
#define OLP  36       // outl pitch in floats

// gx passes between producer/consumer as raw C-fragments:
//   [2 slots][48 tiles][64 lanes] x f32x4, tile = (g*8 + pv)*2 + st
// lane-linear 16B/lane -> contiguous 1KB wave access, conflict-free.
#define NFRAG      48
#define FRAGF      (NFRAG * 64 * 4)                   // floats per slot
#define SMEM_XHX   (2 * FRAGF * 4)                    // 98304
#define SMEM_XHH   (SMEM_XHX + 2 * MS * XP * 2)       // +17408 = 115712
#define SMEM_OUTL  (SMEM_XHH + 2 * MS * XP * 2)       // +17408 = 133120
#define SMEM_PP    (SMEM_OUTL + MS * OLP * 4)         // +4608  = 137728
#define SMEM_TOTAL (SMEM_PP + 2 * 2 * 8 * 16 * 4)     // +2048  = 139776

typedef short bf16x8 __attribute__((ext_vector_type(8)));   // 8 bf16 = 4 VGPRs
typedef float f32x4  __attribute__((ext_vector_type(4)));

// Transposed orientation: A = weights (row = gate-dim), B = x/h (col = seq).
// A-frag and B-frag lane maps are identical, so the same Wfrag bytes and the
// same xh row-reads serve both; C has col(lane&15)=seq, row((lane>>4)*4+i)=dim.
#define MFMA __builtin_amdgcn_mfma_f32_16x16x32_bf16

__device__ __forceinline__ unsigned short f2bf(float f) {
    unsigned u = __float_as_uint(f);
    u += 0x7fffu + ((u >> 16) & 1u);          // round-to-nearest-even
    return (unsigned short)(u >> 16);
}

#if __has_builtin(__builtin_amdgcn_cvt_pk_bf16_f32)
typedef __bf16 bf16x2_t __attribute__((ext_vector_type(2)));
__device__ __forceinline__ unsigned pack2(float a, float b) {
    union { bf16x2_t v; unsigned u; } c;
    c.v = __builtin_amdgcn_cvt_pk_bf16_f32(a, b);
    return c.u;
}
#else
__device__ __forceinline__ unsigned pack2(float a, float b) {
    return (unsigned)f2bf(a) | ((unsigned)f2bf(b) << 16);
}
#endif

__device__ __forceinline__ void pack8(float4 a, float4 b, unsigned short* dst) {
    union { unsigned u[4]; bf16x8 v; } pk;
    pk.u[0] = pack2(a.x, a.y); pk.u[1] = pack2(a.z, a.w);
    pk.u[2] = pack2(b.x, b.y); pk.u[3] = pack2(b.z, b.w);
    *(bf16x8*)dst = pk.v;
}

__device__ __forceinline__ float fast_rcp(float x) {
    return __builtin_amdgcn_rcpf(x);   // v_rcp_f32, ~1 ulp — fine at bf16 output
}

// ---------------------------------------------------------------------------
// Prep: swizzle W_ih / W_hh into per-gate MFMA fragments, bf16. (unchanged)
// Frag index F = ((side*3 + g)*8 + sl)*4 + kk   (side 0=W_ih, 1=W_hh;
// g 0=r,1=z,2=n; sl = 16-dim slice 0..7; kk = K-subtile 0..3).
// Element j of lane (n=lane&15, q=lane>>4):
//   W_side[(g*128 + sl*16 + n) * 128 + (kk*32 + q*8 + j)]
// ---------------------------------------------------------------------------
__global__ void prep_weights(const float* __restrict__ Wih,
                             const float* __restrict__ Whh,
                             unsigned short* __restrict__ Wfrag) {
    int idx  = blockIdx.x * blockDim.x + threadIdx.x;   // 0 .. 98303
    int j    = idx & 7;
    int lane = (idx >> 3) & 63;
    int kk   = (idx >> 9) & 3;
    int sl   = (idx >> 11) & 7;
    int sg   = idx >> 14;            // 0..5 = side*3 + g
    int n = lane & 15, q = lane >> 4;
    int k  = kk * 32 + q * 8 + j;
    int g  = (sg >= 3) ? sg - 3 : sg;
    int gd = g * 128 + sl * 16 + n;
    const float* src = (sg >= 3) ? Whh : Wih;
    Wfrag[idx] = f2bf(src[gd * 128 + k]);
}

// ---------------------------------------------------------------------------
// Wave-specialized GRU, r7 structure (best: ~75us) with two surgical cuts:
//   1. amdgpu_waves_per_eu(4,4): dynamic LDS hides the 1-block/CU limit, so
//      the allocator was minimizing arch-VGPRs (64) and parking MFMA accs in
//      AGPRs -> ~70 accvgpr_read/write per consumer wave per step. Pinning
//      occupancy at 4 waves/EU frees the full 128-reg budget (unified file:
//      MFMA C/D in arch VGPRs, no move traffic).
//   2. Out-projection moved off the producer MFMA path (wofl deleted) to the
//      r8-proven consumer f32-dot + shfl-reduce + Pp handoff: -16 LDS b128
//      reads, -8 MFMA, -divergent straggler; +~16 VALU on consumers.
// ---------------------------------------------------------------------------
__global__ __launch_bounds__(NT, 4)
__attribute__((amdgpu_waves_per_eu(4, 4)))
void gru_mfma(
    const float* __restrict__ x,      // [8192][32][128]
    const float* __restrict__ h0,     // [8192][128]
    const unsigned short* __restrict__ Wfrag,
    const float* __restrict__ b_ih,   // [384]
    const float* __restrict__ b_hh,   // [384]
    const float* __restrict__ w_out,  // [128]
    const float* __restrict__ b_out,  // [1]
    float* __restrict__ out)          // [8192][32]
{
    extern __shared__ char smem[];
    float*          gxf  = (float*)(smem);                       // [2][48][64][4]
    unsigned short* xhx  = (unsigned short*)(smem + SMEM_XHX);   // [2][MS][XP]
    unsigned short* xhh  = (unsigned short*)(smem + SMEM_XHH);   // [2][MS][XP]
    float*          outl = (float*)(smem + SMEM_OUTL);           // [MS][OLP]
    float*          Pp   = (float*)(smem + SMEM_PP);             // [2][2][8][16]

    const int tid  = threadIdx.x;
    const int n0   = blockIdx.x * MS;
    const int wv   = tid >> 6;       // 0..15
    const int lane = tid & 63;
    const int ln   = lane & 15;      // C col = seq within tile
    const int q    = lane >> 4;      // C rows q*4..q*4+3 = gate-dims
    const bf16x8* W = (const bf16x8*)Wfrag;

    if (wv < 8) {
        // ================= CONSUMER =================
        const int d4 = wv * 16 + q * 4;            // first of this lane's 4 dims
        const f32x4 bhn4 = *(const f32x4*)&b_hh[2*DD + d4];
        const f32x4 wo4  = *(const f32x4*)&w_out[d4];

        bf16x8 whr[4], whz[4], whn[4];             // A-operands (W_hh slices)
        #pragma unroll
        for (int kk = 0; kk < 4; ++kk) {
            whr[kk] = W[((24 + wv)*4 + kk)*64 + lane];
            whz[kk] = W[((32 + wv)*4 + kk)*64 + lane];
            whn[kk] = W[((40 + wv)*4 + kk)*64 + lane];
        }

        // stage h0 (bf16) into xhh slot 0
        {
            const int gn = tid >> 4, gd8 = (tid & 15) * 8;
            const float* hb = h0 + (size_t)(n0 + gn) * DD + gd8;
            pack8(*(const float4*)hb, *(const float4*)(hb + 4),
                  &xhh[gn * XP + gd8]);
        }
        // fp32 hidden state: lane=seq(ln), regs = dims d4..d4+3, per seq-tile st
        float4 hp0 = *(const float4*)&h0[(size_t)(n0 + ln) * DD + d4];
        float4 hp1 = *(const float4*)&h0[(size_t)(n0 + 16 + ln) * DD + d4];
        float hprev[8] = {hp0.x, hp0.y, hp0.z, hp0.w,
                          hp1.x, hp1.y, hp1.z, hp1.w};

        __syncthreads();   // #1: staging done
        __syncthreads();   // #2: gx[0] ready

        #pragma unroll 2
        for (int t = 0; t < LL; ++t) {
            const int cur = t & 1;
            const float* gf = gxf + cur * FRAGF;
            f32x4 cr[2], cz[2], ch[2];
            #pragma unroll
            for (int st = 0; st < 2; ++st) {
                cr[st] = *(const f32x4*)&gf[(((0*8 + wv)*2 + st)*64 + lane)*4];
                cz[st] = *(const f32x4*)&gf[(((1*8 + wv)*2 + st)*64 + lane)*4];
                ch[st] = bhn4;                 // b_hn folded into acc init
            }
            const unsigned short* hr0 = xhh + cur*MS*XP + ln*XP;
            const unsigned short* hr1 = hr0 + 16*XP;
            #pragma unroll
            for (int kk = 0; kk < 4; ++kk) {
                bf16x8 b0 = *(const bf16x8*)(hr0 + kk*32 + q*8);
                bf16x8 b1 = *(const bf16x8*)(hr1 + kk*32 + q*8);
                cr[0] = MFMA(whr[kk], b0, cr[0], 0,0,0);
                cr[1] = MFMA(whr[kk], b1, cr[1], 0,0,0);
                cz[0] = MFMA(whz[kk], b0, cz[0], 0,0,0);
                cz[1] = MFMA(whz[kk], b1, cz[1], 0,0,0);
                ch[0] = MFMA(whn[kk], b0, ch[0], 0,0,0);
                ch[1] = MFMA(whn[kk], b1, ch[1], 0,0,0);
            }
            // n-gate x-side preacts read late (short live range)
            f32x4 gnx[2];
            #pragma unroll
            for (int st = 0; st < 2; ++st)
                gnx[st] = *(const f32x4*)&gf[(((2*8 + wv)*2 + st)*64 + lane)*4];

            unsigned short* hw = xhh + (cur ^ 1)*MS*XP;
            float po[2] = {0.f, 0.f};          // out-partials (this lane's dims)
            #pragma unroll
            for (int st = 0; st < 2; ++st) {
                float hh_[4];
                #pragma unroll
                for (int i = 0; i < 4; ++i) {
                    // shared-reciprocal double sigmoid (r4/r7-proven numerics):
                    // 3 exp + 2 rcp per element incl. tanh; e-clamp kills 0*inf
                    const float e1 = fminf(__expf(-cr[st][i]), 1e18f);
                    const float e2 = fminf(__expf(-cz[st][i]), 1e18f);
                    const float p1 = 1.f + e1, p2 = 1.f + e2;
                    const float R  = fast_rcp(p1 * p2);
                    const float rr = R * p2;
                    const float zz = R * p1;
                    const float aa = __builtin_fmaf(rr, ch[st][i], gnx[st][i]);
                    // tanh(aa) = 2/(1+exp(-2a)) - 1 : NaN-free
                    const float ee = __expf(-2.f * aa);
                    const float th = 2.f * fast_rcp(1.f + ee) - 1.f;
                    const float hh = __builtin_fmaf(zz, hprev[st*4+i] - th, th);
                    hprev[st*4+i] = hh;
                    hh_[i] = hh;
                    po[st] = __builtin_fmaf(hh, wo4[i], po[st]);
                }
                union { unsigned u[2]; unsigned long long ull; } hv;
                hv.u[0] = pack2(hh_[0], hh_[1]);
                hv.u[1] = pack2(hh_[2], hh_[3]);
                *(unsigned long long*)&hw[(st*16 + ln)*XP + d4] = hv.ull;
            }
            // out partial: reduce over q-quads (lanes ln, ln+16, ln+32, ln+48)
            {
                float p0 = po[0] + __shfl_xor(po[0], 16);
                p0 += __shfl_xor(p0, 32);
                float p1_ = po[1] + __shfl_xor(po[1], 16);
                p1_ += __shfl_xor(p1_, 32);
                if (lane < 16) {
                    Pp[((cur*2 + 0)*8 + wv)*16 + ln] = p0;
                    Pp[((cur*2 + 1)*8 + wv)*16 + ln] = p1_;
                }
            }
            __syncthreads();   // #3..#34
        }
    } else {
        // ================= PRODUCER =================
        const int pv = wv - 8;
        const int d4 = pv * 16 + q * 4;
        // bake b_ih + b_hh into r,z; b_ih only into n (b_hh n-side is consumer's)
        f32x4 br4, bz4, bn4;
        {
            f32x4 a0 = *(const f32x4*)&b_ih[d4];
            f32x4 a1 = *(const f32x4*)&b_hh[d4];
            br4 = a0 + a1;
            a0 = *(const f32x4*)&b_ih[DD + d4];
            a1 = *(const f32x4*)&b_hh[DD + d4];
            bz4 = a0 + a1;
            bn4 = *(const f32x4*)&b_ih[2*DD + d4];
        }
        const float bo = b_out[0];

        bf16x8 wxr[4], wxz[4], wxn[4];             // A-operands (W_ih slices)
        #pragma unroll
        for (int kk = 0; kk < 4; ++kk) {
            wxr[kk] = W[((0  + pv)*4 + kk)*64 + lane];
            wxz[kk] = W[((8  + pv)*4 + kk)*64 + lane];
            wxn[kk] = W[((16 + pv)*4 + kk)*64 + lane];
        }

        const int pt  = tid & 511;
        const int gn  = pt >> 4;             // staging: seq 0..31
        const int gd8 = (pt & 15) * 8;       // staging: dim 0,8,..,120
        const float* xbase = x + ((size_t)(n0 + gn) * LL) * DD + gd8;

        // prologue: stage x_0 -> slot 0, x_1 -> slot 1
        pack8(*(const float4*)(xbase), *(const float4*)(xbase + 4),
              &xhx[gn * XP + gd8]);
        pack8(*(const float4*)(xbase + DD), *(const float4*)(xbase + DD + 4),
              &xhx[MS*XP + gn * XP + gd8]);

        __syncthreads();   // #1: staging done

#define GX_STEP(TT)                                                            \
        {                                                                      \
            const int sr = (TT) & 1;                                           \
            const unsigned short* xr0 = xhx + sr*MS*XP + ln*XP;                \
            const unsigned short* xr1 = xr0 + 16*XP;                           \
            f32x4 ar[2], az[2], an[2];                                         \
            ar[0] = br4; ar[1] = br4;                                          \
            az[0] = bz4; az[1] = bz4;                                          \
            an[0] = bn4; an[1] = bn4;                                          \
            _Pragma("unroll")                                                  \
            for (int kk = 0; kk < 4; ++kk) {                                   \
                bf16x8 b0 = *(const bf16x8*)(xr0 + kk*32 + q*8);               \
                bf16x8 b1 = *(const bf16x8*)(xr1 + kk*32 + q*8);               \
                ar[0] = MFMA(wxr[kk], b0, ar[0], 0,0,0);                       \
                ar[1] = MFMA(wxr[kk], b1, ar[1], 0,0,0);                       \
                az[0] = MFMA(wxz[kk], b0, az[0], 0,0,0);                       \
                az[1] = MFMA(wxz[kk], b1, az[1], 0,0,0);                       \
                an[0] = MFMA(wxn[kk], b0, an[0], 0,0,0);                       \
                an[1] = MFMA(wxn[kk], b1, an[1], 0,0,0);                       \
            }                                                                  \
            float* gw = gxf + sr * FRAGF;                                      \
            _Pragma("unroll")                                                  \
            for (int st = 0; st < 2; ++st) {                                   \
                *(f32x4*)&gw[(((0*8 + pv)*2 + st)*64 + lane)*4] = ar[st];      \
                *(f32x4*)&gw[(((1*8 + pv)*2 + st)*64 + lane)*4] = az[st];      \
                *(f32x4*)&gw[(((2*8 + pv)*2 + st)*64 + lane)*4] = an[st];      \
            }                                                                  \
        }

        // prologue: gx[0] from x_0
        GX_STEP(0)
        __syncthreads();   // #2: gx[0] ready

        #pragma unroll 2
        for (int t = 0; t < LL; ++t) {
            // issue x_{t+2} loads early (latency hides under gx GEMM)
            float4 sa, sb;
            const int ts = t + 2;
            if (ts < LL) {
                sa = *(const float4*)(xbase + (size_t)ts * DD);
                sb = *(const float4*)(xbase + (size_t)ts * DD + 4);
            }
            // gx[t+1] from x_{t+1}
            if (t + 1 < LL) GX_STEP(t + 1)

            // wave 15: assemble out[t-1] from last step's Pp partials
            if (wv == 15 && t >= 1 && lane < 32) {
                const int ps = (t & 1) ^ 1;
                const int st = lane >> 4, sq = lane & 15;
                float o = bo;
                #pragma unroll
                for (int c = 0; c < 8; ++c)
                    o += Pp[((ps*2 + st)*8 + c)*16 + sq];
                outl[(st*16 + sq)*OLP + (t - 1)] = o;
            }
            // late half of staging: pack + LDS write of x_{t+2}
            if (ts < LL)
                pack8(sa, sb, &xhx[(t & 1)*MS*XP + gn * XP + gd8]);

            __syncthreads();   // #3..#34
        }
#undef GX_STEP
    }

    // join: out[31] from Pp slot 1 (written at t=31), then coalesced flush
    if (wv == 15 && lane < 32) {
        const int st = lane >> 4, sq = lane & 15;
        float o = b_out[0];
        #pragma unroll
        for (int c = 0; c < 8; ++c)
            o += Pp[((1*2 + st)*8 + c)*16 + sq];
        outl[(st*16 + sq)*OLP + (LL - 1)] = o;
    }
    __syncthreads();   // #35: outl complete (uniform join barrier)
    if (tid < 256) {
        const int row = tid >> 3;
        const int t4  = (tid & 7) * 4;
        float4 v = *(const float4*)&outl[row * OLP + t4];
        *(float4*)(out + (size_t)(n0 + row) * LL + t4) = v;
    }
}

extern "C" void kernel_launch(void* const* d_in, const int* in_sizes, int n_in,
                              void* d_out, int out_size, void* d_ws, size_t ws_size,
                              hipStream_t stream) {
    const float* item  = (const float*)d_in[0];
    const float* user  = (const float*)d_in[1];
    const float* W_ih  = (const float*)d_in[2];
    const float* W_hh  = (const float*)d_in[3];
    const float* b_ih  = (const float*)d_in[4];
    const float* b_hh  = (const float*)d_in[5];
    const float* W_out = (const float*)d_in[6];
    const float* b_out = (const float*)d_in[7];
    float* out = (float*)d_out;

    unsigned short* Wfrag = (unsigned short*)d_ws;   // 192 frags * 512 = 98304 bf16

    static bool smem_cfg = false;
    if (!smem_cfg) {
        hipFuncSetAttribute((const void*)gru_mfma,
                            hipFuncAttributeMaxDynamicSharedMemorySize,
                            SMEM_TOTAL);
        smem_cfg = true;
    }

    prep_weights<<<384, 256, 0, stream>>>(W_ih, W_hh, Wfrag);
    gru_mfma<<<NSEQ / MS, NT, SMEM_TOTAL, stream>>>(item, user, Wfrag,
                                                    b_ih, b_hh, W_out, b_out, out);
}